// Round 2
// baseline (216.539 us; speedup 1.0000x reference)
//
#include <hip/hip_runtime.h>
#include <math.h>

#define NB 8192
#define NK 64
#define NGLOBAL 16384
#define INV_T 0.5f   // 1/TEMPERATURE

// ---------------------------------------------------------------------------
// Workspace layout:
//   [0, 64KB)          g2l table (int[NGLOBAL])
//   [64KB, 96KB)       row partials (float[NB])
//   [96KB, 96KB+4)     arrival counter (uint)
// ---------------------------------------------------------------------------

// Kernel 1 (single block): fill g2l with -1, zero the counter, scatter
// g2l[batch_indices[i]] = i. One dispatch instead of memset+scatter.
__global__ __launch_bounds__(1024) void setup_kernel(
    const int* __restrict__ bidx, int* __restrict__ g2l,
    unsigned* __restrict__ counter, int b) {
    const int t = threadIdx.x;
    if (t == 0) *counter = 0u;
    for (int i = t; i < NGLOBAL; i += 1024) g2l[i] = -1;
    __syncthreads();
    for (int i = t; i < b; i += 1024) {
        int g = bidx[i];
        if ((unsigned)g < (unsigned)NGLOBAL) g2l[g] = i;  // OOB dropped
    }
}

// Kernel 2: one block per row.
//  - teacher gather FIRST (prefetches scattered lines -> stream hits cache)
//  - single-pass row stream into registers, block max + sumexp -> lse
//  - wave 0: last-wins dedup, diagonal override, KL pointwise terms
//  - fence+counter last-block pattern folds the final reduce into this kernel
__global__ __launch_bounds__(256) void row_loss_kernel(
    const float* __restrict__ S,        // [NB, NB]
    const float* __restrict__ tscore,   // [NB, NK]
    const int* __restrict__ tindex,     // [NB, NK]
    const int* __restrict__ g2l,        // [NGLOBAL]
    float* __restrict__ row_out,        // [NB]
    unsigned* __restrict__ counter,
    float* __restrict__ out)
{
    const int row = blockIdx.x;
    const int t = threadIdx.x;

    __shared__ int    scol[NK];
    __shared__ float  sscore[NK];
    __shared__ float  sglog[NK];
    __shared__ float  sdiag;
    __shared__ float  sred[4];
    __shared__ int    slast;
    __shared__ double sd[4];

    const float* __restrict__ Srow = S + (size_t)row * NB;

    // ---- teacher gather first (wave 0) ----
    if (t < NK) {
        int gi = tindex[(size_t)row * NK + t];
        gi = min(max(gi, 0), NGLOBAL - 1);           // clip like reference
        int col = g2l[gi];
        if (col == row) col = -1;                    // diag forced to 1.0 later
        scol[t]   = col;
        sscore[t] = tscore[(size_t)row * NK + t];
        sglog[t]  = Srow[col >= 0 ? col : row];      // prefetch gathered line
        if (t == 0) sdiag = Srow[row];
    }

    // ---- stream row into registers (coalesced float4) ----
    const float4* rp = reinterpret_cast<const float4*>(Srow);
    float4 v[8];
#pragma unroll
    for (int i = 0; i < 8; ++i) v[i] = rp[i * 256 + t];

    // ---- block max ----
    float m = -INFINITY;
#pragma unroll
    for (int i = 0; i < 8; ++i)
        m = fmaxf(m, fmaxf(fmaxf(v[i].x, v[i].y), fmaxf(v[i].z, v[i].w)));
#pragma unroll
    for (int off = 32; off >= 1; off >>= 1) m = fmaxf(m, __shfl_xor(m, off));
    if ((t & 63) == 0) sred[t >> 6] = m;
    __syncthreads();
    m = fmaxf(fmaxf(sred[0], sred[1]), fmaxf(sred[2], sred[3]));
    const float Mn = m * INV_T;   // max of x = s/T

    // ---- block sum of exp(x - Mn) ----
    float s = 0.f;
#pragma unroll
    for (int i = 0; i < 8; ++i) {
        s += __expf(fmaf(v[i].x, INV_T, -Mn));
        s += __expf(fmaf(v[i].y, INV_T, -Mn));
        s += __expf(fmaf(v[i].z, INV_T, -Mn));
        s += __expf(fmaf(v[i].w, INV_T, -Mn));
    }
#pragma unroll
    for (int off = 32; off >= 1; off >>= 1) s += __shfl_xor(s, off);
    __syncthreads();                 // all reads of sred (max) done
    if ((t & 63) == 0) sred[t >> 6] = s;
    __syncthreads();
    const float lse = __logf(sred[0] + sred[1] + sred[2] + sred[3]) + Mn;

    // ---- teacher terms (wave 0 computes; all threads stay for barriers) ----
    float term = 0.f;
    if (t < NK) {
        int col = scol[t];
        float sc = sscore[t];
        bool live = (col >= 0);
        if (live) {                  // last write wins (scatter-set semantics)
            for (int k = t + 1; k < NK; ++k)
                if (scol[k] == col) { live = false; break; }
        }
        float part = live ? sc : 0.f;
#pragma unroll
        for (int off = 32; off >= 1; off >>= 1) part += __shfl_xor(part, off);
        const float row_sum = 1.0f + part;   // + diagonal 1.0

        if (live && sc > 0.f) {
            float tv = sc / row_sum;
            float logp = fmaf(sglog[t], INV_T, -lse);
            term = tv * (logf(tv) - logp);
        }
        if (t == 0) {                // diagonal target = 1/row_sum
            float td = 1.0f / row_sum;
            float logp = fmaf(sdiag, INV_T, -lse);
            term += td * (logf(td) - logp);
        }
#pragma unroll
        for (int off = 32; off >= 1; off >>= 1) term += __shfl_xor(term, off);
    }

    // ---- publish row partial; last block reduces (deterministic order) ----
    if (t == 0) {
        row_out[row] = term;
        __threadfence();                           // release row_out
        unsigned old = atomicAdd(counter, 1u);     // device-scope
        slast = (old == (unsigned)(NB - 1)) ? 1 : 0;
    }
    __syncthreads();
    if (slast) {
        __threadfence();                           // acquire others' row_out
        double acc = 0.0;
        for (int i = t; i < NB; i += 256) acc += (double)row_out[i];
#pragma unroll
        for (int off = 32; off >= 1; off >>= 1) acc += __shfl_xor(acc, off);
        if ((t & 63) == 0) sd[t >> 6] = acc;
        __syncthreads();
        if (t == 0) {
            double total = sd[0] + sd[1] + sd[2] + sd[3];
            out[0] = (float)(total / (double)NB * 4.0);  // * T^2
        }
    }
}

extern "C" void kernel_launch(void* const* d_in, const int* in_sizes, int n_in,
                              void* d_out, int out_size, void* d_ws, size_t ws_size,
                              hipStream_t stream) {
    const float* S      = (const float*)d_in[0];   // student_logits [B,B] f32
    const float* tscore = (const float*)d_in[1];   // teacher_scores [B,K] f32
    const int*   bidx   = (const int*)d_in[2];     // batch_indices [B] i32
    const int*   tindex = (const int*)d_in[3];     // teacher_indices [B,K] i32
    float* out = (float*)d_out;
    const int b = in_sizes[2];                     // = NB

    int*      g2l     = (int*)d_ws;
    float*    row_out = (float*)((char*)d_ws + NGLOBAL * sizeof(int));
    unsigned* counter = (unsigned*)((char*)d_ws + NGLOBAL * sizeof(int) + NB * sizeof(float));

    setup_kernel<<<1, 1024, 0, stream>>>(bidx, g2l, counter, b);
    row_loss_kernel<<<NB, 256, 0, stream>>>(S, tscore, tindex, g2l, row_out, counter, out);
}

// Round 3
// 64.553 us; speedup vs baseline: 3.3544x; 3.3544x over previous
//
#include <hip/hip_runtime.h>
#include <math.h>

#define NB 8192
#define NK 64
#define NGLOBAL 16384
#define INV_T 0.5f   // 1/TEMPERATURE

// ---------------------------------------------------------------------------
// Workspace layout:
//   [0, 64KB)     g2l table (int[NGLOBAL]) — NEVER initialized; entries are
//                 validated by bidx[col]==gi, so poison/stale values are
//                 rejected (scatter rewrites the same live entries each call).
//   [64KB, 96KB)  row partials (float[NB])
// ---------------------------------------------------------------------------

// Kernel 1: scatter g2l[batch_indices[i]] = i. No fill needed (see above).
__global__ __launch_bounds__(256) void scatter_kernel(
    const int* __restrict__ bidx, int* __restrict__ g2l, int b) {
    int i = blockIdx.x * blockDim.x + threadIdx.x;
    if (i < b) {
        int g = bidx[i];
        if ((unsigned)g < (unsigned)NGLOBAL) g2l[g] = i;  // OOB dropped
    }
}

// Kernel 2: one block (256 thr) per row.
//  - fused single-pass stream: load float4 -> exp -> accumulate (no max pass;
//    logits/T is well within f32 exp range, and a second pass would double
//    HBM traffic — R1/R2 disasm evidence: VGPR_Count=24 => loads remat'd)
//  - wave 0 then handles the <=64 teacher entries: validated g2l lookup,
//    last-wins dedup via __shfl, diagonal override, KL pointwise terms
__global__ __launch_bounds__(256) void row_loss_kernel(
    const float* __restrict__ S,        // [NB, NB]
    const float* __restrict__ tscore,   // [NB, NK]
    const int* __restrict__ tindex,     // [NB, NK]
    const int* __restrict__ g2l,        // [NGLOBAL]
    const int* __restrict__ bidx,       // [NB]
    float* __restrict__ row_out)        // [NB]
{
    const int row = blockIdx.x;
    const int t = threadIdx.x;
    const float* __restrict__ Srow = S + (size_t)row * NB;
    const float4* rp = reinterpret_cast<const float4*>(Srow);

    // ---- single-pass sum of exp(s/T) ----
    float s = 0.f;
#pragma unroll
    for (int i = 0; i < 8; ++i) {
        float4 v = rp[i * 256 + t];
        s += __expf(v.x * INV_T);
        s += __expf(v.y * INV_T);
        s += __expf(v.z * INV_T);
        s += __expf(v.w * INV_T);
    }
#pragma unroll
    for (int off = 32; off >= 1; off >>= 1) s += __shfl_xor(s, off);
    __shared__ float sred[4];
    if ((t & 63) == 0) sred[t >> 6] = s;
    __syncthreads();
    const float lse = __logf(sred[0] + sred[1] + sred[2] + sred[3]);

    if (t >= NK) return;   // waves 1..3 done; wave 0 (64 lanes) continues

    // ---- teacher entries ----
    int gi = tindex[(size_t)row * NK + t];
    gi = min(max(gi, 0), NGLOBAL - 1);             // clip like reference
    int col = g2l[gi];
    bool valid = ((unsigned)col < (unsigned)NB) && (bidx[col] == gi);
    if (valid && col == row) valid = false;        // diagonal forced to 1.0
    float sc = tscore[(size_t)row * NK + t];

    int mycol = valid ? col : -1;
    bool live = valid;
    // last write wins (scatter .set semantics): killed if a later lane
    // writes the same column
    for (int k = t + 1; k < NK; ++k) {
        int ck = __shfl(mycol, k);
        if (valid && ck == mycol) live = false;
    }

    float part = live ? sc : 0.f;                  // sum of surviving scatters
#pragma unroll
    for (int off = 32; off >= 1; off >>= 1) part += __shfl_xor(part, off);
    const float row_sum = 1.0f + part;             // + diagonal 1.0

    float term = 0.f;
    if (live && sc > 0.f) {
        float tv = sc / row_sum;
        float logp = fmaf(Srow[mycol], INV_T, -lse);   // gathered line: L2-hot
        term = tv * (__logf(tv) - logp);
    }
    if (t == 0) {                                  // diagonal target
        float td = 1.0f / row_sum;
        float logp = fmaf(Srow[row], INV_T, -lse);
        term += td * (__logf(td) - logp);
    }
#pragma unroll
    for (int off = 32; off >= 1; off >>= 1) term += __shfl_xor(term, off);
    if (t == 0) row_out[row] = term;
}

// Kernel 3: reduce 8192 row partials -> scalar loss (double accumulation).
__global__ __launch_bounds__(256) void final_reduce_kernel(
    const float* __restrict__ row_out, float* __restrict__ out) {
    double acc = 0.0;
    for (int i = threadIdx.x; i < NB; i += 256) acc += (double)row_out[i];
#pragma unroll
    for (int off = 32; off >= 1; off >>= 1) acc += __shfl_xor(acc, off);
    __shared__ double sd[4];
    if ((threadIdx.x & 63) == 0) sd[threadIdx.x >> 6] = acc;
    __syncthreads();
    if (threadIdx.x == 0) {
        double total = sd[0] + sd[1] + sd[2] + sd[3];
        out[0] = (float)(total / (double)NB * 4.0);   // * T^2
    }
}

extern "C" void kernel_launch(void* const* d_in, const int* in_sizes, int n_in,
                              void* d_out, int out_size, void* d_ws, size_t ws_size,
                              hipStream_t stream) {
    const float* S      = (const float*)d_in[0];   // student_logits [B,B] f32
    const float* tscore = (const float*)d_in[1];   // teacher_scores [B,K] f32
    const int*   bidx   = (const int*)d_in[2];     // batch_indices [B] i32
    const int*   tindex = (const int*)d_in[3];     // teacher_indices [B,K] i32
    float* out = (float*)d_out;
    const int b = in_sizes[2];                     // = NB

    int*   g2l     = (int*)d_ws;
    float* row_out = (float*)((char*)d_ws + NGLOBAL * sizeof(int));

    scatter_kernel<<<(b + 255) / 256, 256, 0, stream>>>(bidx, g2l, b);
    row_loss_kernel<<<NB, 256, 0, stream>>>(S, tscore, tindex, g2l, bidx, row_out);
    final_reduce_kernel<<<1, 256, 0, stream>>>(row_out, out);
}

// Round 4
// 57.264 us; speedup vs baseline: 3.7814x; 1.1273x over previous
//
#include <hip/hip_runtime.h>
#include <math.h>

#define NB 8192
#define NK 64
#define NGLOBAL 16384
#define INV_T 0.5f             // 1/TEMPERATURE
#define C_EXP2 0.72134752044448170f  // log2(e)/2 : exp2(x*C) == exp(x/2)

// ---------------------------------------------------------------------------
// Workspace layout:
//   [0, 64KB)     g2l table (int[NGLOBAL]) — never initialized; lookups are
//                 validated with bidx[col]==gi so stale/poison entries can
//                 never pass (bidx is a permutation-free id list).
//   [64KB, 96KB)  row partials (float[NB])
// ---------------------------------------------------------------------------

// Kernel 1: scatter g2l[batch_indices[i]] = i.
__global__ __launch_bounds__(256) void scatter_kernel(
    const int* __restrict__ bidx, int* __restrict__ g2l, int b) {
    int i = blockIdx.x * blockDim.x + threadIdx.x;
    if (i < b) {
        int g = bidx[i];
        if ((unsigned)g < (unsigned)NGLOBAL) g2l[g] = i;  // OOB dropped
    }
}

// Kernel 2: one block (256 thr) per row, single-pass stream + teacher terms.
__global__ __launch_bounds__(256) void row_loss_kernel(
    const float* __restrict__ S,        // [NB, NB]
    const float* __restrict__ tscore,   // [NB, NK]
    const int* __restrict__ tindex,     // [NB, NK]
    const int* __restrict__ g2l,        // [NGLOBAL]
    const int* __restrict__ bidx,       // [NB]
    float* __restrict__ row_out)        // [NB]
{
    const int row = blockIdx.x;
    const int t = threadIdx.x;
    const float* __restrict__ Srow = S + (size_t)row * NB;
    const float4* rp = reinterpret_cast<const float4*>(Srow);

    // ---- issue all 8 stream loads (32 VGPRs of payload, MLP=8) ----
    float4 v[8];
#pragma unroll
    for (int i = 0; i < 8; ++i) v[i] = rp[i * 256 + t];

    // ---- teacher prefetch (wave 0): dependent chain hides under exp phase --
    int col = -1; bool valid = false; float sc = 0.f, gl = 0.f, gd = 0.f;
    if (t < NK) {
        int gi = tindex[(size_t)row * NK + t];
        gi = min(max(gi, 0), NGLOBAL - 1);           // clip like reference
        col = g2l[gi];
        valid = ((unsigned)col < (unsigned)NB) && (bidx[col] == gi)
                && (col != row);                     // diag forced later
        sc = tscore[(size_t)row * NK + t];
        gl = Srow[valid ? col : row];                // gathered student logit
        gd = Srow[row];                              // diagonal logit (bcast)
    }

    // Loads cannot sink past a may-write asm: forces them all in flight now.
    asm volatile("" ::: "memory");

    // ---- sum of exp(s/T) via exact identity exp2(s*log2e/2) ----
    float s0 = 0.f, s1 = 0.f, s2 = 0.f, s3 = 0.f;
#pragma unroll
    for (int i = 0; i < 8; ++i) {
        s0 += exp2f(v[i].x * C_EXP2);
        s1 += exp2f(v[i].y * C_EXP2);
        s2 += exp2f(v[i].z * C_EXP2);
        s3 += exp2f(v[i].w * C_EXP2);
    }
    float s = (s0 + s1) + (s2 + s3);
#pragma unroll
    for (int off = 32; off >= 1; off >>= 1) s += __shfl_xor(s, off);
    __shared__ float sred[4];
    if ((t & 63) == 0) sred[t >> 6] = s;
    __syncthreads();
    const float lse = __logf((sred[0] + sred[1]) + (sred[2] + sred[3]));

    if (t >= NK) return;   // waves 1..3 done; wave 0 (64 lanes) continues

    // ---- last-write-wins dedup (uniform loop, all 64 lanes active) ----
    int mycol = valid ? col : -1;
    bool live = valid;
#pragma unroll 1
    for (int k = 1; k < NK; ++k) {
        int ck = __shfl(mycol, k);
        if (valid && t < k && ck == mycol) live = false;
    }

    float part = live ? sc : 0.f;                  // sum of surviving scatters
#pragma unroll
    for (int off = 32; off >= 1; off >>= 1) part += __shfl_xor(part, off);
    const float row_sum = 1.0f + part;             // + diagonal 1.0

    float term = 0.f;
    if (live && sc > 0.f) {
        float tv = sc / row_sum;
        float logp = fmaf(gl, INV_T, -lse);
        term = tv * (__logf(tv) - logp);
    }
    if (t == 0) {                                  // diagonal target
        float td = 1.0f / row_sum;
        float logp = fmaf(gd, INV_T, -lse);
        term += td * (__logf(td) - logp);
    }
#pragma unroll
    for (int off = 32; off >= 1; off >>= 1) term += __shfl_xor(term, off);
    if (t == 0) row_out[row] = term;
}

// Kernel 3: reduce 8192 row partials -> scalar (vectorized, double accum).
__global__ __launch_bounds__(256) void final_reduce_kernel(
    const float* __restrict__ row_out, float* __restrict__ out) {
    const int t = threadIdx.x;
    const float4* rp = reinterpret_cast<const float4*>(row_out);
    float4 w[8];
#pragma unroll
    for (int i = 0; i < 8; ++i) w[i] = rp[i * 256 + t];
    asm volatile("" ::: "memory");
    double acc = 0.0;
#pragma unroll
    for (int i = 0; i < 8; ++i)
        acc += (double)((w[i].x + w[i].y) + (w[i].z + w[i].w));
#pragma unroll
    for (int off = 32; off >= 1; off >>= 1) acc += __shfl_xor(acc, off);
    __shared__ double sd[4];
    if ((t & 63) == 0) sd[t >> 6] = acc;
    __syncthreads();
    if (t == 0) {
        double total = (sd[0] + sd[1]) + (sd[2] + sd[3]);
        out[0] = (float)(total / (double)NB * 4.0);   // * T^2
    }
}

extern "C" void kernel_launch(void* const* d_in, const int* in_sizes, int n_in,
                              void* d_out, int out_size, void* d_ws, size_t ws_size,
                              hipStream_t stream) {
    const float* S      = (const float*)d_in[0];   // student_logits [B,B] f32
    const float* tscore = (const float*)d_in[1];   // teacher_scores [B,K] f32
    const int*   bidx   = (const int*)d_in[2];     // batch_indices [B] i32
    const int*   tindex = (const int*)d_in[3];     // teacher_indices [B,K] i32
    float* out = (float*)d_out;
    const int b = in_sizes[2];                     // = NB

    int*   g2l     = (int*)d_ws;
    float* row_out = (float*)((char*)d_ws + NGLOBAL * sizeof(int));

    scatter_kernel<<<(b + 255) / 256, 256, 0, stream>>>(bidx, g2l, b);
    row_loss_kernel<<<NB, 256, 0, stream>>>(S, tscore, tindex, g2l, bidx, row_out);
    final_reduce_kernel<<<1, 256, 0, stream>>>(row_out, out);
}